// Round 4
// baseline (409.393 us; speedup 1.0000x reference)
//
#include <hip/hip_runtime.h>
#include <math.h>

typedef __attribute__((ext_vector_type(8))) short short8;
typedef __attribute__((ext_vector_type(4))) float floatx4;

#define SQ 2048
#define NH 16
#define HD 128
#define NB 2
#define DM 2048
#define QKV_N 6144

__device__ __forceinline__ unsigned short f2bf(float f) {
  unsigned int x = __builtin_bit_cast(unsigned int, f);
  unsigned int r = x + 0x7fffu + ((x >> 16) & 1u);
  return (unsigned short)(r >> 16);
}
__device__ __forceinline__ float bf2f(unsigned short u) {
  unsigned int x = ((unsigned int)u) << 16;
  return __builtin_bit_cast(float, x);
}
__device__ __forceinline__ void store_c(unsigned short* p, float v) { *p = f2bf(v); }
__device__ __forceinline__ void store_c(float* p, float v) { *p = v; }

// ---------------- fp32 -> bf16 conversion for x, w_qkv, w_out in one launch ----------------
#define N4_X  (NB * SQ * DM / 4)
#define N4_WQ (3 * DM * DM / 4)
#define N4_WO (DM * DM / 4)
__global__ __launch_bounds__(256) void cvt_all(const float* __restrict__ x,
                                               const float* __restrict__ wq,
                                               const float* __restrict__ wo,
                                               unsigned short* __restrict__ x_b,
                                               unsigned short* __restrict__ wq_b,
                                               unsigned short* __restrict__ wo_b) {
  int i = blockIdx.x * blockDim.x + threadIdx.x;
  const float* src;
  unsigned short* dst;
  if (i < N4_X) {
    src = x; dst = x_b;
  } else if (i < N4_X + N4_WQ) {
    i -= N4_X; src = wq; dst = wq_b;
  } else {
    i -= N4_X + N4_WQ; src = wo; dst = wo_b;
  }
  const float4 v = ((const float4*)src)[i];
  ushort4 o;
  o.x = f2bf(v.x); o.y = f2bf(v.y); o.z = f2bf(v.z); o.w = f2bf(v.w);
  ((ushort4*)dst)[i] = o;
}

// ---------------- GEMM: C[M,N] = A[M,K] (bf16) @ W[N,K]^T (bf16) ----------------
// m97 structure: 128x128 tile, 4 waves, 4x4 16x16x32 MFMA, global_load_lds width=16.
// (kept for the out-proj GEMM: N=2048 -> 512 blocks = 2/CU suits this structure)
template <typename OutT>
__global__ __launch_bounds__(256, 2) void gemm_bt(
    const unsigned short* __restrict__ A, const unsigned short* __restrict__ W,
    OutT* __restrict__ C, int M, int N, int K) {
  __shared__ __align__(16) unsigned short As[128 * 32];
  __shared__ __align__(16) unsigned short Ws[128 * 32];
  const int tid = threadIdx.x;
  const int lane = tid & 63;
  const int w = tid >> 6;
  const int wr = w >> 1, wc = w & 1;
  const int t16 = lane & 15, quad = lane >> 4;

  const long long rowA0 = (long long)blockIdx.y * 128;
  const long long colB0 = (long long)blockIdx.x * 128;
  const unsigned short* Abase = A + rowA0 * K;
  const unsigned short* Wbase = W + colB0 * K;

  const int c0 = tid, c1 = tid + 256;
  const int r0 = c0 >> 2, o0 = (c0 & 3) * 8;
  const int r1 = c1 >> 2, o1 = (c1 & 3) * 8;

  floatx4 acc[4][4] = {};

  for (int k0 = 0; k0 < K; k0 += 32) {
    __syncthreads();
    __builtin_amdgcn_global_load_lds(
        (const __attribute__((address_space(1))) void*)(Abase + (long long)r0 * K + k0 + o0),
        (__attribute__((address_space(3))) void*)(As + c0 * 8), 16, 0, 0);
    __builtin_amdgcn_global_load_lds(
        (const __attribute__((address_space(1))) void*)(Abase + (long long)r1 * K + k0 + o1),
        (__attribute__((address_space(3))) void*)(As + c1 * 8), 16, 0, 0);
    __builtin_amdgcn_global_load_lds(
        (const __attribute__((address_space(1))) void*)(Wbase + (long long)r0 * K + k0 + o0),
        (__attribute__((address_space(3))) void*)(Ws + c0 * 8), 16, 0, 0);
    __builtin_amdgcn_global_load_lds(
        (const __attribute__((address_space(1))) void*)(Wbase + (long long)r1 * K + k0 + o1),
        (__attribute__((address_space(3))) void*)(Ws + c1 * 8), 16, 0, 0);
    __syncthreads();

    short8 a[4], b[4];
#pragma unroll
    for (int i = 0; i < 4; i++)
      a[i] = *(const short8*)(As + (wr * 64 + i * 16 + t16) * 32 + quad * 8);
#pragma unroll
    for (int j = 0; j < 4; j++)
      b[j] = *(const short8*)(Ws + (wc * 64 + j * 16 + t16) * 32 + quad * 8);
#pragma unroll
    for (int i = 0; i < 4; i++)
#pragma unroll
      for (int j = 0; j < 4; j++)
        acc[i][j] = __builtin_amdgcn_mfma_f32_16x16x32_bf16(a[i], b[j], acc[i][j], 0, 0, 0);
  }

#pragma unroll
  for (int i = 0; i < 4; i++) {
    const int rt = wr * 64 + i * 16 + quad * 4;
#pragma unroll
    for (int j = 0; j < 4; j++) {
      const long long col = colB0 + wc * 64 + j * 16 + t16;
#pragma unroll
      for (int r = 0; r < 4; r++) {
        const long long row = rowA0 + rt + r;
        store_c(&C[row * N + col], acc[i][j][r]);
      }
    }
  }
}

// ---------------- GEMM 128x384, BK=64, 8 waves, phase-pipelined counted-lgkm schedule ------
// R3 control skeleton (proven) at a quantization-free grid: M/128 x N/384 = 32x16 = 512
// blocks = exactly 2 full rounds of 256 CUs; every CU does exactly 2 tiles (vs 384-block
// grid's worst-case 2 of 256x256 tiles = 1.33x more work on the critical CU).
// Wave tile 64x96 (2x4 wave grid), acc[4][6]. LDS: A slots [2 parity][2 khalf][128][32]
// (8KB each, 32KB), B slots [2][2][384][32] (24KB each, 96KB) -> 128KB, 1 block/CU.
// Same XOR swizzle as the measured-0-conflict R3 layout on both A and B (64B row stride):
// read elem = (quad*8) ^ ((t16>>1&3)<<3); staged via pre-swizzled global source col.
// Stage issues per phase: 2; khalf1(t+1) staged P1/P2, khalf0(t+2) staged P3/P4;
// vmcnt(6) certify at P2 (khalf1(t)) and P4 (khalf0(t+1)) -> identical count algebra to R3.
// lgkm-counted register prefetch: P1/P3 issue 2 ds_reads (wait lgkmcnt(2)), P2/P4 issue 8
// (wait lgkmcnt(8)). K-summation order unchanged -> same numerics as gemm_bt.
#define GLL16(srcp, ldsp)                                                      \
  __builtin_amdgcn_global_load_lds(                                            \
      (const __attribute__((address_space(1))) void*)(srcp),                   \
      (__attribute__((address_space(3))) void*)(ldsp), 16, 0, 0)

#define SBAR() __builtin_amdgcn_s_barrier()
#define SCHED() __builtin_amdgcn_sched_barrier(0)

__device__ __forceinline__ void lda2(short8 (&v)[2], const unsigned short* s, int base) {
#pragma unroll
  for (int i = 0; i < 2; i++) v[i] = *(const short8*)(s + base + i * 512);
}
__device__ __forceinline__ void lda6(short8 (&v)[6], const unsigned short* s, int base) {
#pragma unroll
  for (int j = 0; j < 6; j++) v[j] = *(const short8*)(s + base + j * 512);
}

__device__ __forceinline__ void mfma12(floatx4 (&acc)[4][6], const short8 (&a)[2],
                                       const short8 (&b)[6], const int i0) {
#pragma unroll
  for (int i = 0; i < 2; i++)
#pragma unroll
    for (int j = 0; j < 6; j++)
      acc[i0 + i][j] =
          __builtin_amdgcn_mfma_f32_16x16x32_bf16(a[i], b[j], acc[i0 + i][j], 0, 0, 0);
}

__global__ __launch_bounds__(512, 2) void gemm256(
    const unsigned short* __restrict__ A, const unsigned short* __restrict__ W,
    unsigned short* __restrict__ C, int M, int N, int K) {
  __shared__ __align__(16) unsigned short AS[4 * 4096];   // [p][h][128][32]
  __shared__ __align__(16) unsigned short BS[4 * 12288];  // [p][h][384][32]

  const int tid = threadIdx.x;
  const int lane = tid & 63;
  const int w = tid >> 6;
  const int wr = w >> 2, wc = w & 3;            // 2 x 4 wave grid; wave tile 64x96
  const int t16 = lane & 15, quad = lane >> 4;

  // XCD swizzle (512 % 8 == 0); bx fastest within a chunk -> A-panel L2 reuse
  const int nbx = N / 384;
  const int cpx = gridDim.x >> 3;
  const int id = (blockIdx.x & 7) * cpx + (blockIdx.x >> 3);
  const int by = id / nbx, bx = id % nbx;

  const long long rowA0 = (long long)by * 128;
  const long long colB0 = (long long)bx * 384;

  // staging geometry: thread t -> row t/4 (+128c for B chunks), swizzled col group
  const int srow = tid >> 2;
  const int scol = (((tid & 3) ^ ((tid >> 3) & 3)) << 3);
  const unsigned short* Asrc = A + (rowA0 + srow) * K + scol;
  const unsigned short* Bsrc = W + (colB0 + srow) * K + scol;
  const long long BCK = (long long)128 * K;  // B chunk row-stride in elements

  // slot bases: [parity][khalf]
  unsigned short* const A00 = AS;
  unsigned short* const A01 = AS + 4096;
  unsigned short* const A10 = AS + 8192;
  unsigned short* const A11 = AS + 12288;
  unsigned short* const B00 = BS;
  unsigned short* const B01 = BS + 12288;
  unsigned short* const B10 = BS + 24576;
  unsigned short* const B11 = BS + 36864;

#define GLLA(slot, kc) GLL16(Asrc + (kc), (slot) + tid * 8)
#define GLLB1(slot, kc, c) GLL16(Bsrc + (c) * BCK + (kc), (slot) + (c) * 4096 + tid * 8)
#define GLLB(slot, kc)          \
  do {                          \
    GLLB1(slot, kc, 0);         \
    GLLB1(slot, kc, 1);         \
    GLLB1(slot, kc, 2);         \
  } while (0)

  // read geometry (element units; slot row stride 32)
  const int swE = ((t16 >> 1) & 3) << 3;
  const int aRd = (wr * 64 + t16) * 32 + ((quad * 8) ^ swE);
  const int bRd = (wc * 96 + t16) * 32 + ((quad * 8) ^ swE);

  floatx4 acc[4][6] = {};
  const int NT = K >> 6;

  // prologue: kh0(0) kh1(0) kh0(1); 12 issues; certify first 4 (kh0(0)) -> vmcnt(8)
  GLLA(A00, 0);
  GLLB(B00, 0);
  GLLA(A01, 32);
  GLLB(B01, 32);
  GLLA(A10, 64);
  GLLB(B10, 64);
  asm volatile("s_waitcnt vmcnt(8)");
  SBAR();
  SCHED();

  short8 aR[2], aS[2], bR[6], bS[6];
  lda2(aR, A00, aRd);      // F1(0) fragments
  lda6(bR, B00, bRd);
  SCHED();

#pragma unroll 2
  for (int t = 0; t < NT; ++t) {
    const int p = t & 1;
    unsigned short* const Ap0 = p ? A10 : A00;
    unsigned short* const Ap1 = p ? A11 : A01;
    unsigned short* const Bp1 = p ? B11 : B01;
    unsigned short* const Aq0 = p ? A00 : A10;
    unsigned short* const Bq0 = p ? B00 : B10;
    unsigned short* const Aq1 = p ? A01 : A11;
    unsigned short* const Bq1 = p ? B01 : B11;
    // tail: clamp source k (garbage into never-consumed slots keeps vmcnt bookkeeping uniform)
    const int kk1 = ((t + 1 < NT) ? (t + 1) << 6 : 0) + 32;  // kh1(t+1)
    const int kk2 = (t + 2 < NT) ? (t + 2) << 6 : 0;         // kh0(t+2)

    // ---- P1: MFMA aR x bR (rows0-1, kh0); stage Ak1(t+1)+Bk1(t+1)c0; prefetch aS ----
    SBAR();                 // WAR: kh1(t-1) reads done (lgkm(8)@P4(t-1)) before stage lands
    SCHED();
    GLLA(Aq1, kk1);
    GLLB1(Bq1, kk1, 0);
    lda2(aS, Ap0, aRd + 1024);
    SCHED();
    asm volatile("s_waitcnt lgkmcnt(2)");   // prev-phase reads done; own 2 in flight
    SCHED();
    __builtin_amdgcn_s_setprio(1);
    mfma12(acc, aR, bR, 0);
    __builtin_amdgcn_s_setprio(0);
    SCHED();

    // ---- P2: certify kh1(t); MFMA aS x bR (rows2-3); stage Bk1(t+1)c1,c2; prefetch kh1 ----
    asm volatile("s_waitcnt vmcnt(6)");     // kh1(t) landed (issued P1/P2 of t-1)
    SBAR();
    SCHED();
    GLLB1(Bq1, kk1, 1);
    GLLB1(Bq1, kk1, 2);
    lda2(aR, Ap1, aRd);
    lda6(bS, Bp1, bRd);
    SCHED();
    asm volatile("s_waitcnt lgkmcnt(8)");
    SCHED();
    __builtin_amdgcn_s_setprio(1);
    mfma12(acc, aS, bR, 2);
    __builtin_amdgcn_s_setprio(0);
    SCHED();

    // ---- P3: MFMA aR x bS (rows0-1, kh1); stage Ak0(t+2)+Bk0(t+2)c0; prefetch aS ----
    SBAR();                 // WAR: kh0(t) reads done (lgkm(8)@P2) before stage lands
    SCHED();
    GLLA(Ap0, kk2);
    GLLB1(Bq0 == B00 ? B10 : B00, kk2, 0);  // kh0 parity-p slot = Bp0
    lda2(aS, Ap1, aRd + 1024);
    SCHED();
    asm volatile("s_waitcnt lgkmcnt(2)");
    SCHED();
    __builtin_amdgcn_s_setprio(1);
    mfma12(acc, aR, bS, 0);
    __builtin_amdgcn_s_setprio(0);
    SCHED();

    // ---- P4: certify kh0(t+1); MFMA aS x bS (rows2-3); stage Bk0(t+2)c1,c2; prefetch F1 ----
    asm volatile("s_waitcnt vmcnt(6)");     // kh0(t+1) landed (issued P3/P4 of t-1)
    SBAR();
    SCHED();
    GLLB1(Bq0 == B00 ? B10 : B00, kk2, 1);
    GLLB1(Bq0 == B00 ? B10 : B00, kk2, 2);
    lda2(aR, Aq0, aRd);
    lda6(bR, Bq0, bRd);
    SCHED();
    asm volatile("s_waitcnt lgkmcnt(8)");
    SCHED();
    __builtin_amdgcn_s_setprio(1);
    mfma12(acc, aS, bS, 2);
    __builtin_amdgcn_s_setprio(0);
    SCHED();
  }

  // drain trailing (clamped) stages before LDS could be reassigned at endpgm
  asm volatile("s_waitcnt vmcnt(0)");

#pragma unroll
  for (int i = 0; i < 4; i++) {
    const long long rt = rowA0 + wr * 64 + i * 16 + quad * 4;
#pragma unroll
    for (int j = 0; j < 6; j++) {
      const long long col = colB0 + wc * 96 + j * 16 + t16;
#pragma unroll
      for (int r = 0; r < 4; r++)
        C[(rt + r) * N + col] = f2bf(acc[i][j][r]);
    }
  }
#undef GLLA
#undef GLLB1
#undef GLLB
}

// ---------------- RoPE + L2 norm + scale; Q,K only -> (B,H,S,HD) ----------------
__global__ __launch_bounds__(256) void rope_norm(
    const unsigned short* __restrict__ qkv, const float* __restrict__ freqs,
    const float* __restrict__ scale_p,
    unsigned short* __restrict__ Qn, unsigned short* __restrict__ Kn) {
  const int lane = threadIdx.x & 63;
  const int g = blockIdx.x * 4 + (threadIdx.x >> 6);  // b*32768 + s*16 + h
  const int h = g & 15;
  const int s = (g >> 4) & 2047;
  const int b = g >> 15;
  const float scale = *scale_p;

  const unsigned short* qp = qkv + ((long long)(b * SQ + s)) * QKV_N + h * HD + 2 * lane;
  const unsigned int q2 = *(const unsigned int*)(qp);
  const unsigned int k2 = *(const unsigned int*)(qp + DM);
  const float2 f2 = *(const float2*)(freqs + ((long long)s * 64 + lane) * 2);

  const float fc = f2.x, fs = f2.y;
  const float q0 = bf2f((unsigned short)(q2 & 0xffff)), q1 = bf2f((unsigned short)(q2 >> 16));
  const float k0 = bf2f((unsigned short)(k2 & 0xffff)), k1 = bf2f((unsigned short)(k2 >> 16));

  const float qr = q0 * fc - q1 * fs, qi = q0 * fs + q1 * fc;
  const float kr = k0 * fc - k1 * fs, ki = k0 * fs + k1 * fc;

  float sq = qr * qr + qi * qi;
  float sk = kr * kr + ki * ki;
#pragma unroll
  for (int m = 1; m < 64; m <<= 1) {
    sq += __shfl_xor(sq, m);
    sk += __shfl_xor(sk, m);
  }
  const float qs = scale / (sqrtf(sq) + 1e-6f);
  const float ks = 1.0f / (sqrtf(sk) + 1e-6f);

  const long long oidx = ((long long)(b * NH + h) * SQ + s) * HD + 2 * lane;
  *(unsigned int*)(Qn + oidx) = (unsigned int)f2bf(qr * qs) | ((unsigned int)f2bf(qi * qs) << 16);
  *(unsigned int*)(Kn + oidx) = (unsigned int)f2bf(kr * ks) | ((unsigned int)f2bf(ki * ks) << 16);
}

// ---------------- flash attention (causal), fixed-max softmax, 64-key blocks ----------------
// 256-thread blocks (4 waves x 16 q-rows = 64-row band); band pair (pb, 31-pb)
// -> uniform 33 x 64-key iterations; 512 blocks = 2/CU.
// V read directly from qkv (row stride QKV_N).
__global__ __launch_bounds__(256, 2) void attn(
    const unsigned short* __restrict__ Qn, const unsigned short* __restrict__ Kn,
    const unsigned short* __restrict__ qkv, const float* __restrict__ scale_p,
    unsigned short* __restrict__ Oout) {
  __shared__ __align__(16) unsigned short Ks[64 * 136];   // K rows, padded stride 136
  __shared__ __align__(16) unsigned short Vt[128 * 72];   // V transposed [d][key], stride 72
  __shared__ __align__(16) unsigned short Pw[4][16 * 72]; // per-wave P, stride 72

  const int tid = threadIdx.x;
  const int lane = tid & 63;
  const int w = tid >> 6;
  const int t16 = lane & 15, quad = lane >> 4;
  // XCD swizzle: k%8 = xcd; each xcd gets 4 consecutive heads (L2 locality)
  const int k = blockIdx.x;            // 0..511
  const int xcd = k & 7, i = k >> 3;   // i 0..63
  const int bh = (xcd << 2) | (i & 3); // 0..31
  const int pb = i >> 2;               // 0..15: band pair (pb, 31-pb), 64-row bands
  const float M = *scale_p;
  const long long base = (long long)bh * SQ * HD;
  const int b = bh >> 4, h = bh & 15;
  const unsigned short* Vbase = qkv + 2 * DM + h * HD + (long long)b * SQ * QKV_N;
  unsigned short* pw = &Pw[w][0];

#pragma unroll
  for (int t = 0; t < 2; t++) {
    const int qb = (t == 0) ? 64 * pb : 64 * (31 - pb);

    // Q fragments (A layout: m=t16, k=quad*8+j)
    short8 qf[4];
    const int qrow = qb + w * 16 + t16;
#pragma unroll
    for (int c = 0; c < 4; c++)
      qf[c] = *(const short8*)(Qn + base + (long long)qrow * HD + c * 32 + quad * 8);

    floatx4 o[8] = {};
    float l[4] = {0.f, 0.f, 0.f, 0.f};
    const int qr0 = qb + w * 16 + quad * 4;  // C-layout row base
    const int kend = qb + 64;

    for (int kb = 0; kb < kend; kb += 64) {
      __syncthreads();
      // stage K rows [kb, kb+64), padded stride 136 (256 threads x 4 uint4)
#pragma unroll
      for (int cc = 0; cc < 4; cc++) {
        const int c = tid + cc * 256;
        const int row = c >> 4, off = (c & 15) * 8;
        const uint4 d = *(const uint4*)(Kn + base + (long long)(kb + row) * HD + off);
        *(uint4*)(Ks + row * 136 + off) = d;
      }
      // stage V transposed from qkv (row stride QKV_N): 256 threads x 2 pack-units
#pragma unroll
      for (int cc = 0; cc < 2; cc++) {
        const int idx = tid + cc * 256;
        const int kk0 = (idx & 31) * 2;     // key pair 0..62
        const int d0 = (idx >> 5) * 8;      // dim group 0..120
        const unsigned short* vp = Vbase + (long long)(kb + kk0) * QKV_N + d0;
        const short8 v0 = *(const short8*)(vp);
        const short8 v1 = *(const short8*)(vp + QKV_N);
#pragma unroll
        for (int jj = 0; jj < 8; jj++) {
          const unsigned int pk = (unsigned int)(unsigned short)v0[jj] |
                                  ((unsigned int)(unsigned short)v1[jj] << 16);
          *(unsigned int*)(Vt + (d0 + jj) * 72 + kk0) = pk;
        }
      }
      __syncthreads();

      // scores: 16 q x 64 keys, fp32 accum
      floatx4 sc[4];
#pragma unroll
      for (int g = 0; g < 4; g++) {
        floatx4 s = {};
        const unsigned short* kr = Ks + (g * 16 + t16) * 136 + quad * 8;
#pragma unroll
        for (int c = 0; c < 4; c++)
          s = __builtin_amdgcn_mfma_f32_16x16x32_bf16(qf[c], *(const short8*)(kr + c * 32), s, 0, 0, 0);
        sc[g] = s;
      }
      // fixed-max softmax (scores <= M by construction) + causal mask -> p, l
#pragma unroll
      for (int r = 0; r < 4; r++) {
        const int qr = qr0 + r;
        float e[4];
#pragma unroll
        for (int g = 0; g < 4; g++) {
          float ee = __expf(sc[g][r] - M);
          e[g] = (kb + g * 16 + t16 <= qr) ? ee : 0.f;
        }
        l[r] += (e[0] + e[1]) + (e[2] + e[3]);
#pragma unroll
        for (int g = 0; g < 4; g++)
          pw[(quad * 4 + r) * 72 + g * 16 + t16] = f2bf(e[g]);
      }
      asm volatile("s_waitcnt lgkmcnt(0)" ::: "memory");  // same-wave LDS RAW fence
      const short8 pf0 = *(const short8*)(pw + t16 * 72 + quad * 8);
      const short8 pf1 = *(const short8*)(pw + t16 * 72 + 32 + quad * 8);
      // PV over both 32-key halves: B frags contiguous 16B per lane from Vt
#pragma unroll
      for (int dc = 0; dc < 8; dc++) {
        const unsigned short* vc = Vt + (dc * 16 + t16) * 72;
        o[dc] = __builtin_amdgcn_mfma_f32_16x16x32_bf16(pf0, *(const short8*)(vc + quad * 8), o[dc], 0, 0, 0);
        o[dc] = __builtin_amdgcn_mfma_f32_16x16x32_bf16(pf1, *(const short8*)(vc + 32 + quad * 8), o[dc], 0, 0, 0);
      }
    }

    // l: reduce across the 16 lanes of the quad-row group, then epilogue
    float linv[4];
#pragma unroll
    for (int r = 0; r < 4; r++) {
      float s = l[r];
      s += __shfl_xor(s, 1);
      s += __shfl_xor(s, 2);
      s += __shfl_xor(s, 4);
      s += __shfl_xor(s, 8);
      linv[r] = 1.0f / s;
    }
#pragma unroll
    for (int dc = 0; dc < 8; dc++)
#pragma unroll
      for (int r = 0; r < 4; r++) {
        const int q = qb + w * 16 + quad * 4 + r;
        Oout[(long long)(b * SQ + q) * DM + h * HD + dc * 16 + t16] =
            f2bf(o[dc][r] * linv[r]);
      }
  }
}

extern "C" void kernel_launch(void* const* d_in, const int* in_sizes, int n_in,
                              void* d_out, int out_size, void* d_ws, size_t ws_size,
                              hipStream_t stream) {
  const float* x = (const float*)d_in[0];
  const float* freqs = (const float*)d_in[1];
  const float* w_qkv = (const float*)d_in[2];
  const float* w_out = (const float*)d_in[3];
  const float* attn_scale = (const float*)d_in[4];
  float* out = (float*)d_out;

  char* ws = (char*)d_ws;
  // [0, 50331648)          qkv bf16 4096x6144 (live through attn: V read in-place)
  // [50331648, +16M each)  Qn / Kn bf16 (B,H,S,HD)
  // [100663296, +16M)      x_b bf16 (dead after gemm1; re-used as attn_o)
  // [117440512, +25M)      w_qkv_b
  // [142606336, +8M)       w_out_b
  unsigned short* qkv = (unsigned short*)ws;
  unsigned short* Qn = (unsigned short*)(ws + 50331648);
  unsigned short* Kn = Qn + (size_t)NB * NH * SQ * HD;
  unsigned short* x_b = (unsigned short*)(ws + 100663296);
  unsigned short* attn_o = x_b;  // alias: x_b dead after gemm1
  unsigned short* w_qkv_b = (unsigned short*)(ws + 117440512);
  unsigned short* w_out_b = (unsigned short*)(ws + 142606336);

  cvt_all<<<dim3((N4_X + N4_WQ + N4_WO + 255) / 256), 256, 0, stream>>>(
      x, w_qkv, w_out, x_b, w_qkv_b, w_out_b);

  // QKV projection: 128x384 phase-pipelined kernel, 32x16 = 512 tiles = 2 exact rounds
  gemm256<<<dim3(512), 512, 0, stream>>>(
      x_b, w_qkv_b, qkv, NB * SQ, QKV_N, DM);
  rope_norm<<<dim3((NB * SQ * NH) / 4), 256, 0, stream>>>(qkv, freqs, attn_scale, Qn, Kn);
  attn<<<dim3(512), 256, 0, stream>>>(Qn, Kn, qkv, attn_scale, attn_o);
  gemm_bt<float><<<dim3(DM / 128, (NB * SQ) / 128), 256, 0, stream>>>(
      attn_o, w_out_b, out, NB * SQ, DM, DM);
}

// Round 5
// 396.486 us; speedup vs baseline: 1.0326x; 1.0326x over previous
//
#include <hip/hip_runtime.h>
#include <math.h>

typedef __attribute__((ext_vector_type(8))) short short8;
typedef __attribute__((ext_vector_type(4))) float floatx4;

#define SQ 2048
#define NH 16
#define HD 128
#define NB 2
#define DM 2048
#define QKV_N 6144

__device__ __forceinline__ unsigned short f2bf(float f) {
  unsigned int x = __builtin_bit_cast(unsigned int, f);
  unsigned int r = x + 0x7fffu + ((x >> 16) & 1u);
  return (unsigned short)(r >> 16);
}
__device__ __forceinline__ float bf2f(unsigned short u) {
  unsigned int x = ((unsigned int)u) << 16;
  return __builtin_bit_cast(float, x);
}
__device__ __forceinline__ void store_c(unsigned short* p, float v) { *p = f2bf(v); }
__device__ __forceinline__ void store_c(float* p, float v) { *p = v; }

// ---------------- fp32 -> bf16 conversion for x, w_qkv, w_out in one launch ----------------
#define N4_X  (NB * SQ * DM / 4)
#define N4_WQ (3 * DM * DM / 4)
#define N4_WO (DM * DM / 4)
__global__ __launch_bounds__(256) void cvt_all(const float* __restrict__ x,
                                               const float* __restrict__ wq,
                                               const float* __restrict__ wo,
                                               unsigned short* __restrict__ x_b,
                                               unsigned short* __restrict__ wq_b,
                                               unsigned short* __restrict__ wo_b) {
  int i = blockIdx.x * blockDim.x + threadIdx.x;
  const float* src;
  unsigned short* dst;
  if (i < N4_X) {
    src = x; dst = x_b;
  } else if (i < N4_X + N4_WQ) {
    i -= N4_X; src = wq; dst = wq_b;
  } else {
    i -= N4_X + N4_WQ; src = wo; dst = wo_b;
  }
  const float4 v = ((const float4*)src)[i];
  ushort4 o;
  o.x = f2bf(v.x); o.y = f2bf(v.y); o.z = f2bf(v.z); o.w = f2bf(v.w);
  ((ushort4*)dst)[i] = o;
}

// ---------------- GEMM 128xBN, BK=64, 8 waves, 2-phase/K-tile counted schedule ------------
// Phase-merged evolution of the R4 kernel (measured: phase ~= MFMA_cluster + ~550cy fixed
// overhead at both 16-MFMA/1120cy and 12-MFMA/1060cy points). 2 phases per K-tile, each a
// 4xBNF=24(16) MFMA cluster -> overhead fraction drops to ~37%(47%).
// Block tile 128 x BN (BN = BNF*64); wave grid 2x4, wave tile 64 x BNF*16; acc[4][BNF].
// LDS slots [parity][khalf]: A [128][32] (8KB, 1 GLL issue), B [BN][32] (BN*64B, BISS
// issues of 128 rows each). 0-conflict XOR swizzle (R3/R4-measured): read col
// (quad*8)^(((t16>>1)&3)<<3), pre-applied to global source col for linear GLL dest.
// Schedule per K-tile t (p=t&1, q=!p):
//  P1: vmcnt(1+BISS) certify kh1(t); SBAR; stage kh1(t+1)->[q]; prefetch kh1(t) frags [p];
//      lgkm(4+BNF); MFMA aRxbR (kh0(t), read prev phase).
//  P2: vmcnt(1+BISS) certify kh0(t+1); SBAR; stage kh0(t+2)->[p]; prefetch kh0(t+1) [q];
//      lgkm(4+BNF); MFMA aSxbS (kh1(t)).
// Certify lead = 2 phases (~3000cy >> 900cy HBM). WAR: a slot's reads are lgkm-certified
// one phase before the barrier that precedes its re-stage. Tail clamps keep counts uniform.
// K order per acc element: kh0 then kh1, t ascending == R4/gemm_bt -> bitwise-same C.
#define GLL16(srcp, ldsp)                                                      \
  __builtin_amdgcn_global_load_lds(                                            \
      (const __attribute__((address_space(1))) void*)(srcp),                   \
      (__attribute__((address_space(3))) void*)(ldsp), 16, 0, 0)

#define SBAR() __builtin_amdgcn_s_barrier()
#define SCHED() __builtin_amdgcn_sched_barrier(0)

template <int N> __device__ __forceinline__ void wait_vm() {
  if constexpr (N == 3) asm volatile("s_waitcnt vmcnt(3)");
  else if constexpr (N == 4) asm volatile("s_waitcnt vmcnt(4)");
  else if constexpr (N == 6) asm volatile("s_waitcnt vmcnt(6)");
  else if constexpr (N == 8) asm volatile("s_waitcnt vmcnt(8)");
}
template <int N> __device__ __forceinline__ void wait_lgkm() {
  if constexpr (N == 8) asm volatile("s_waitcnt lgkmcnt(8)");
  else if constexpr (N == 10) asm volatile("s_waitcnt lgkmcnt(10)");
}

template <int NF>
__device__ __forceinline__ void ldaN(short8 (&v)[NF], const unsigned short* s, int base) {
#pragma unroll
  for (int i = 0; i < NF; i++) v[i] = *(const short8*)(s + base + i * 512);
}

template <int BNF>
__device__ __forceinline__ void mfmaN(floatx4 (&acc)[4][BNF], const short8 (&a)[4],
                                      const short8 (&b)[BNF]) {
#pragma unroll
  for (int i = 0; i < 4; i++)
#pragma unroll
    for (int j = 0; j < BNF; j++)
      acc[i][j] = __builtin_amdgcn_mfma_f32_16x16x32_bf16(a[i], b[j], acc[i][j], 0, 0, 0);
}

template <int BNF, typename OutT>
__global__ __launch_bounds__(512, 2) void gemm2ph(
    const unsigned short* __restrict__ A, const unsigned short* __restrict__ W,
    OutT* __restrict__ C, int M, int N, int K) {
  constexpr int BN = BNF * 64;        // block cols (384 or 256)
  constexpr int BSLOT = BN * 32;      // elements per B slot
  constexpr int BISS = BN / 128;      // GLL issues per B slot (3 or 2)
  constexpr int VMS = 1 + BISS;       // steady vmcnt
  constexpr int LG = 4 + BNF;         // lgkm count (phase prefetch reads)
  __shared__ __align__(16) unsigned short AS[4 * 4096];
  __shared__ __align__(16) unsigned short BS[4 * BSLOT];

  const int tid = threadIdx.x;
  const int lane = tid & 63;
  const int w = tid >> 6;
  const int wr = w >> 2, wc = w & 3;  // 2 x 4 wave grid; wave tile 64 x BNF*16
  const int t16 = lane & 15, quad = lane >> 4;

  // XCD swizzle (grid % 8 == 0); bx fastest within a chunk -> A-panel L2 reuse
  const int nbx = N / BN;
  const int cpx = gridDim.x >> 3;
  const int id = (blockIdx.x & 7) * cpx + (blockIdx.x >> 3);
  const int by = id / nbx, bx = id % nbx;

  const long long rowA0 = (long long)by * 128;
  const long long colB0 = (long long)bx * BN;

  // staging geometry: thread t -> row t/4 (+128c for B chunks), swizzled col group
  const int srow = tid >> 2;
  const int scol = (((tid & 3) ^ ((tid >> 3) & 3)) << 3);
  const unsigned short* Asrc = A + (rowA0 + srow) * K + scol;
  const unsigned short* Bsrc = W + (colB0 + srow) * K + scol;
  const long long BCK = (long long)128 * K;  // B chunk row-stride in elements

  // slot bases: [parity][khalf]
  unsigned short* const A00 = AS;
  unsigned short* const A01 = AS + 4096;
  unsigned short* const A10 = AS + 8192;
  unsigned short* const A11 = AS + 12288;
  unsigned short* const B00 = BS;
  unsigned short* const B01 = BS + BSLOT;
  unsigned short* const B10 = BS + 2 * BSLOT;
  unsigned short* const B11 = BS + 3 * BSLOT;

#define GLLA(slot, kc) GLL16(Asrc + (kc), (slot) + tid * 8)
#define GLLB(slot, kc)                                                \
  do {                                                                \
    _Pragma("unroll")                                                 \
    for (int c = 0; c < BISS; c++)                                    \
      GLL16(Bsrc + c * BCK + (kc), (slot) + c * 4096 + tid * 8);      \
  } while (0)

  // read geometry (element units; slot row stride 32)
  const int swE = ((t16 >> 1) & 3) << 3;
  const int aRd = (wr * 64 + t16) * 32 + ((quad * 8) ^ swE);
  const int bRd = (wc * (BNF * 16) + t16) * 32 + ((quad * 8) ^ swE);

  floatx4 acc[4][BNF] = {};
  const int NT = K >> 6;

  // prologue: kh0(0)->par0, kh1(0)->par0, kh0(1)->par1; certify kh0(0) -> vmcnt(2*VMS)
  GLLA(A00, 0);
  GLLB(B00, 0);
  GLLA(A01, 32);
  GLLB(B01, 32);
  GLLA(A10, 64);
  GLLB(B10, 64);
  wait_vm<2 * VMS>();
  SBAR();
  SCHED();

  short8 aR[4], aS[4], bR[BNF], bS[BNF];
  ldaN<4>(aR, A00, aRd);  // kh0(0) fragments
  ldaN<BNF>(bR, B00, bRd);
  SCHED();

#pragma unroll 2
  for (int t = 0; t < NT; ++t) {
    const int p = t & 1;
    unsigned short* const Akh1p = p ? A11 : A01;  // read: kh1(t) frags
    unsigned short* const Bkh1p = p ? B11 : B01;
    unsigned short* const Akh1q = p ? A01 : A11;  // stage: kh1(t+1)
    unsigned short* const Bkh1q = p ? B01 : B11;
    unsigned short* const Akh0q = p ? A00 : A10;  // read: kh0(t+1) frags
    unsigned short* const Bkh0q = p ? B00 : B10;
    unsigned short* const Akh0p = p ? A10 : A00;  // stage: kh0(t+2)
    unsigned short* const Bkh0p = p ? B10 : B00;
    // tail: clamp source k (garbage into never-consumed slots keeps counts uniform)
    const int kk1 = ((t + 1 < NT) ? (t + 1) << 6 : 0) + 32;  // kh1(t+1)
    const int kk2 = (t + 2 < NT) ? (t + 2) << 6 : 0;         // kh0(t+2)

    // ---- P1: certify kh1(t); MFMA kh0(t) = aR x bR; stage kh1(t+1); prefetch kh1(t) ----
    wait_vm<VMS>();
    SBAR();
    SCHED();
    GLLA(Akh1q, kk1);
    GLLB(Bkh1q, kk1);
    ldaN<4>(aS, Akh1p, aRd);
    ldaN<BNF>(bS, Bkh1p, bRd);
    SCHED();
    wait_lgkm<LG>();  // prev-phase frag reads done; own LG in flight
    SCHED();
    __builtin_amdgcn_s_setprio(1);
    mfmaN<BNF>(acc, aR, bR);
    __builtin_amdgcn_s_setprio(0);
    SCHED();

    // ---- P2: certify kh0(t+1); MFMA kh1(t) = aS x bS; stage kh0(t+2); prefetch kh0(t+1) --
    wait_vm<VMS>();
    SBAR();
    SCHED();
    GLLA(Akh0p, kk2);
    GLLB(Bkh0p, kk2);
    ldaN<4>(aR, Akh0q, aRd);
    ldaN<BNF>(bR, Bkh0q, bRd);
    SCHED();
    wait_lgkm<LG>();
    SCHED();
    __builtin_amdgcn_s_setprio(1);
    mfmaN<BNF>(acc, aS, bS);
    __builtin_amdgcn_s_setprio(0);
    SCHED();
  }

  // drain trailing (clamped) stages before LDS could be reassigned at endpgm
  asm volatile("s_waitcnt vmcnt(0)");

#pragma unroll
  for (int i = 0; i < 4; i++) {
    const long long rt = rowA0 + wr * 64 + i * 16 + quad * 4;
#pragma unroll
    for (int j = 0; j < BNF; j++) {
      const long long col = colB0 + wc * (BNF * 16) + j * 16 + t16;
#pragma unroll
      for (int r = 0; r < 4; r++)
        store_c(&C[(rt + r) * N + col], acc[i][j][r]);
    }
  }
#undef GLLA
#undef GLLB
}

// ---------------- RoPE + L2 norm + scale; Q,K only -> (B,H,S,HD) ----------------
__global__ __launch_bounds__(256) void rope_norm(
    const unsigned short* __restrict__ qkv, const float* __restrict__ freqs,
    const float* __restrict__ scale_p,
    unsigned short* __restrict__ Qn, unsigned short* __restrict__ Kn) {
  const int lane = threadIdx.x & 63;
  const int g = blockIdx.x * 4 + (threadIdx.x >> 6);  // b*32768 + s*16 + h
  const int h = g & 15;
  const int s = (g >> 4) & 2047;
  const int b = g >> 15;
  const float scale = *scale_p;

  const unsigned short* qp = qkv + ((long long)(b * SQ + s)) * QKV_N + h * HD + 2 * lane;
  const unsigned int q2 = *(const unsigned int*)(qp);
  const unsigned int k2 = *(const unsigned int*)(qp + DM);
  const float2 f2 = *(const float2*)(freqs + ((long long)s * 64 + lane) * 2);

  const float fc = f2.x, fs = f2.y;
  const float q0 = bf2f((unsigned short)(q2 & 0xffff)), q1 = bf2f((unsigned short)(q2 >> 16));
  const float k0 = bf2f((unsigned short)(k2 & 0xffff)), k1 = bf2f((unsigned short)(k2 >> 16));

  const float qr = q0 * fc - q1 * fs, qi = q0 * fs + q1 * fc;
  const float kr = k0 * fc - k1 * fs, ki = k0 * fs + k1 * fc;

  float sq = qr * qr + qi * qi;
  float sk = kr * kr + ki * ki;
#pragma unroll
  for (int m = 1; m < 64; m <<= 1) {
    sq += __shfl_xor(sq, m);
    sk += __shfl_xor(sk, m);
  }
  const float qs = scale / (sqrtf(sq) + 1e-6f);
  const float ks = 1.0f / (sqrtf(sk) + 1e-6f);

  const long long oidx = ((long long)(b * NH + h) * SQ + s) * HD + 2 * lane;
  *(unsigned int*)(Qn + oidx) = (unsigned int)f2bf(qr * qs) | ((unsigned int)f2bf(qi * qs) << 16);
  *(unsigned int*)(Kn + oidx) = (unsigned int)f2bf(kr * ks) | ((unsigned int)f2bf(ki * ks) << 16);
}

// ---------------- flash attention (causal), fixed-max softmax, 64-key blocks ----------------
// 256-thread blocks (4 waves x 16 q-rows = 64-row band); band pair (pb, 31-pb)
// -> uniform 33 x 64-key iterations; 512 blocks = 2/CU.
// V read directly from qkv (row stride QKV_N).
__global__ __launch_bounds__(256, 2) void attn(
    const unsigned short* __restrict__ Qn, const unsigned short* __restrict__ Kn,
    const unsigned short* __restrict__ qkv, const float* __restrict__ scale_p,
    unsigned short* __restrict__ Oout) {
  __shared__ __align__(16) unsigned short Ks[64 * 136];   // K rows, padded stride 136
  __shared__ __align__(16) unsigned short Vt[128 * 72];   // V transposed [d][key], stride 72
  __shared__ __align__(16) unsigned short Pw[4][16 * 72]; // per-wave P, stride 72

  const int tid = threadIdx.x;
  const int lane = tid & 63;
  const int w = tid >> 6;
  const int t16 = lane & 15, quad = lane >> 4;
  // XCD swizzle: k%8 = xcd; each xcd gets 4 consecutive heads (L2 locality)
  const int k = blockIdx.x;            // 0..511
  const int xcd = k & 7, i = k >> 3;   // i 0..63
  const int bh = (xcd << 2) | (i & 3); // 0..31
  const int pb = i >> 2;               // 0..15: band pair (pb, 31-pb), 64-row bands
  const float M = *scale_p;
  const long long base = (long long)bh * SQ * HD;
  const int b = bh >> 4, h = bh & 15;
  const unsigned short* Vbase = qkv + 2 * DM + h * HD + (long long)b * SQ * QKV_N;
  unsigned short* pw = &Pw[w][0];

#pragma unroll
  for (int t = 0; t < 2; t++) {
    const int qb = (t == 0) ? 64 * pb : 64 * (31 - pb);

    // Q fragments (A layout: m=t16, k=quad*8+j)
    short8 qf[4];
    const int qrow = qb + w * 16 + t16;
#pragma unroll
    for (int c = 0; c < 4; c++)
      qf[c] = *(const short8*)(Qn + base + (long long)qrow * HD + c * 32 + quad * 8);

    floatx4 o[8] = {};
    float l[4] = {0.f, 0.f, 0.f, 0.f};
    const int qr0 = qb + w * 16 + quad * 4;  // C-layout row base
    const int kend = qb + 64;

    for (int kb = 0; kb < kend; kb += 64) {
      __syncthreads();
      // stage K rows [kb, kb+64), padded stride 136 (256 threads x 4 uint4)
#pragma unroll
      for (int cc = 0; cc < 4; cc++) {
        const int c = tid + cc * 256;
        const int row = c >> 4, off = (c & 15) * 8;
        const uint4 d = *(const uint4*)(Kn + base + (long long)(kb + row) * HD + off);
        *(uint4*)(Ks + row * 136 + off) = d;
      }
      // stage V transposed from qkv (row stride QKV_N): 256 threads x 2 pack-units
#pragma unroll
      for (int cc = 0; cc < 2; cc++) {
        const int idx = tid + cc * 256;
        const int kk0 = (idx & 31) * 2;     // key pair 0..62
        const int d0 = (idx >> 5) * 8;      // dim group 0..120
        const unsigned short* vp = Vbase + (long long)(kb + kk0) * QKV_N + d0;
        const short8 v0 = *(const short8*)(vp);
        const short8 v1 = *(const short8*)(vp + QKV_N);
#pragma unroll
        for (int jj = 0; jj < 8; jj++) {
          const unsigned int pk = (unsigned int)(unsigned short)v0[jj] |
                                  ((unsigned int)(unsigned short)v1[jj] << 16);
          *(unsigned int*)(Vt + (d0 + jj) * 72 + kk0) = pk;
        }
      }
      __syncthreads();

      // scores: 16 q x 64 keys, fp32 accum
      floatx4 sc[4];
#pragma unroll
      for (int g = 0; g < 4; g++) {
        floatx4 s = {};
        const unsigned short* kr = Ks + (g * 16 + t16) * 136 + quad * 8;
#pragma unroll
        for (int c = 0; c < 4; c++)
          s = __builtin_amdgcn_mfma_f32_16x16x32_bf16(qf[c], *(const short8*)(kr + c * 32), s, 0, 0, 0);
        sc[g] = s;
      }
      // fixed-max softmax (scores <= M by construction) + causal mask -> p, l
#pragma unroll
      for (int r = 0; r < 4; r++) {
        const int qr = qr0 + r;
        float e[4];
#pragma unroll
        for (int g = 0; g < 4; g++) {
          float ee = __expf(sc[g][r] - M);
          e[g] = (kb + g * 16 + t16 <= qr) ? ee : 0.f;
        }
        l[r] += (e[0] + e[1]) + (e[2] + e[3]);
#pragma unroll
        for (int g = 0; g < 4; g++)
          pw[(quad * 4 + r) * 72 + g * 16 + t16] = f2bf(e[g]);
      }
      asm volatile("s_waitcnt lgkmcnt(0)" ::: "memory");  // same-wave LDS RAW fence
      const short8 pf0 = *(const short8*)(pw + t16 * 72 + quad * 8);
      const short8 pf1 = *(const short8*)(pw + t16 * 72 + 32 + quad * 8);
      // PV over both 32-key halves: B frags contiguous 16B per lane from Vt
#pragma unroll
      for (int dc = 0; dc < 8; dc++) {
        const unsigned short* vc = Vt + (dc * 16 + t16) * 72;
        o[dc] = __builtin_amdgcn_mfma_f32_16x16x32_bf16(pf0, *(const short8*)(vc + quad * 8), o[dc], 0, 0, 0);
        o[dc] = __builtin_amdgcn_mfma_f32_16x16x32_bf16(pf1, *(const short8*)(vc + 32 + quad * 8), o[dc], 0, 0, 0);
      }
    }

    // l: reduce across the 16 lanes of the quad-row group, then epilogue
    float linv[4];
#pragma unroll
    for (int r = 0; r < 4; r++) {
      float s = l[r];
      s += __shfl_xor(s, 1);
      s += __shfl_xor(s, 2);
      s += __shfl_xor(s, 4);
      s += __shfl_xor(s, 8);
      linv[r] = 1.0f / s;
    }
#pragma unroll
    for (int dc = 0; dc < 8; dc++)
#pragma unroll
      for (int r = 0; r < 4; r++) {
        const int q = qb + w * 16 + quad * 4 + r;
        Oout[(long long)(b * SQ + q) * DM + h * HD + dc * 16 + t16] =
            f2bf(o[dc][r] * linv[r]);
      }
  }
}

extern "C" void kernel_launch(void* const* d_in, const int* in_sizes, int n_in,
                              void* d_out, int out_size, void* d_ws, size_t ws_size,
                              hipStream_t stream) {
  const float* x = (const float*)d_in[0];
  const float* freqs = (const float*)d_in[1];
  const float* w_qkv = (const float*)d_in[2];
  const float* w_out = (const float*)d_in[3];
  const float* attn_scale = (const float*)d_in[4];
  float* out = (float*)d_out;

  char* ws = (char*)d_ws;
  // [0, 50331648)          qkv bf16 4096x6144 (live through attn: V read in-place)
  // [50331648, +16M each)  Qn / Kn bf16 (B,H,S,HD)
  // [100663296, +16M)      x_b bf16 (dead after gemm1; re-used as attn_o)
  // [117440512, +25M)      w_qkv_b
  // [142606336, +8M)       w_out_b
  unsigned short* qkv = (unsigned short*)ws;
  unsigned short* Qn = (unsigned short*)(ws + 50331648);
  unsigned short* Kn = Qn + (size_t)NB * NH * SQ * HD;
  unsigned short* x_b = (unsigned short*)(ws + 100663296);
  unsigned short* attn_o = x_b;  // alias: x_b dead after gemm1
  unsigned short* w_qkv_b = (unsigned short*)(ws + 117440512);
  unsigned short* w_out_b = (unsigned short*)(ws + 142606336);

  cvt_all<<<dim3((N4_X + N4_WQ + N4_WO + 255) / 256), 256, 0, stream>>>(
      x, w_qkv, w_out, x_b, w_qkv_b, w_out_b);

  // QKV projection: 128x384 2-phase kernel, 32x16 = 512 tiles = 2 exact rounds
  gemm2ph<6, unsigned short><<<dim3(512), 512, 0, stream>>>(
      x_b, w_qkv_b, qkv, NB * SQ, QKV_N, DM);
  rope_norm<<<dim3((NB * SQ * NH) / 4), 256, 0, stream>>>(qkv, freqs, attn_scale, Qn, Kn);
  attn<<<dim3(512), 256, 0, stream>>>(Qn, Kn, qkv, attn_scale, attn_o);
  // out-proj: 128x256 2-phase kernel, 32x8 = 256 tiles = 1 exact round
  gemm2ph<4, float><<<dim3(256), 512, 0, stream>>>(
      attn_o, w_out_b, out, NB * SQ, DM, DM);
}